// Round 3
// baseline (359.812 us; speedup 1.0000x reference)
//
#include <hip/hip_runtime.h>
#include <math.h>

// AFM forward: out[b] = linear(b) + softmax-weighted pair-interaction projection.
// B=4096, F=26, d=64, P=325 pairs, af=64.
//
// R10: split each row across 2 waves (11 m-tiles each) + R8-style depth-1
// prefetch restored. R9 post-mortem: afm = 43.8 us, MfmaUtil 9.5 / VALU 37 /
// HBM 12% / occupancy 27.5% -> latency-bound, under-occupied (16 waves/CU
// grid cap), and R9's un-prefetched 2-tile loop exposed LDS latency at each
// iteration head (regression 113->121 total). Fix:
//  (a) 2 waves per row, tiles 0..10 / 11..21 (tile 21 all pads) -> grid
//      2048 blocks = 32 waves/CU cap (2x), per-wave chain 21 -> 11 steps.
//  (b) per-iteration structure back to R8: one tile, prefetch next tile's
//      tab+emb fragments during current tile's MFMAs.
//  (c) flash 2-partition merge: each wave reduces to scalar (m,l,rr) in
//      red_s, one extra __syncthreads, h=0 wave combines and writes.
// LDS 17.1 KB/block (9 blocks/CU); VGPR ~64 (8 waves/SIMD) -> full 32/CU.

#define NF 26
#define NP 325
#define NHT 11           // m-tiles per half-row wave
#define NTILE 22         // 2 halves x 11 tiles = 352 pair slots (>=NP pad)
#define ED 64
#define AF 64
#define NDENSE 13
#define RPB 2            // rows per block
#define WPB 4            // waves per block = RPB rows x 2 halves
#define BLOCK (WPB * 64)
#define ESTRIDE 72       // f16 elems per emb row: 144 B (16B-aligned rows)
#define WSTRIDE 72       // f16 elems per w1t row: 144 B (16B-aligned rows)

typedef __attribute__((ext_vector_type(8))) _Float16 half8;
typedef __attribute__((ext_vector_type(4))) float f32x4;

__device__ __forceinline__ half8 bcast8(float v) {
    _Float16 hh = (_Float16)v;
    half8 r = { hh, hh, hh, hh, hh, hh, hh, hh };
    return r;
}

__global__ __launch_bounds__(BLOCK, 4)   // VGPR cap 128 (R4 lesson: never cap below live set)
void afm_kernel(const int*   __restrict__ sparse,   // [B,26]
                const float* __restrict__ dense,    // [B,13]
                const float* __restrict__ etab,     // [V,64]
                const float* __restrict__ ltab,     // [V]
                const float* __restrict__ wdense,   // [13]
                const float* __restrict__ bias,     // [1]
                const float* __restrict__ W1,       // [64][64] f32, d-major
                const float* __restrict__ b1,       // [64]
                const float* __restrict__ w2,       // [64]
                const float* __restrict__ proj,     // [64]
                float*       __restrict__ out,      // [B]
                int B)
{
    const int t    = threadIdx.x;
    const int wave = t >> 6;
    const int lane = t & 63;
    const int qd   = lane >> 4;     // quad 0..3
    const int ln   = lane & 15;
    const int lr   = wave >> 1;     // local row 0..1
    const int h    = wave & 1;      // tile-half 0..1

    __shared__ alignas(16) _Float16       w1t_s[AF][WSTRIDE];        // 9216 B
    __shared__              unsigned short tab_s[NTILE * 16];        //  704 B
    __shared__ alignas(16) _Float16       emb_all[RPB][NF][ESTRIDE]; // 7488 B
    __shared__              float          red_s[WPB][4];            //   64 B

    // ---- block-cooperative embedding staging: RPB rows spread evenly over
    //      256 threads (416 tasks), f32 gather -> f16 b128 LDS writes ----
    for (int task = t; task < RPB * NF * 8; task += BLOCK) {
        int w   = task / (NF * 8);
        int rem = task - w * (NF * 8);
        int f = rem >> 3, c = rem & 7;                   // 8-half chunk
        int rw = blockIdx.x * RPB + w;
        if (rw < B) {
            const float* src = etab + (size_t)sparse[rw * NF + f] * ED + c * 8;
            float4 v0 = *(const float4*)(src);
            float4 v1 = *(const float4*)(src + 4);
            half8 hv = { (_Float16)v0.x, (_Float16)v0.y, (_Float16)v0.z, (_Float16)v0.w,
                         (_Float16)v1.x, (_Float16)v1.y, (_Float16)v1.z, (_Float16)v1.w };
            *(half8*)(&emb_all[w][f][c * 8]) = hv;
        }
    }
    // ---- block-cooperative W1 -> W1^T staging (L2-hot 16 KB) ----
    for (int idx = t; idx < ED * AF; idx += BLOCK) {
        int d = idx >> 6, a = idx & 63;       // W1 is [d][a]
        w1t_s[a][d] = (_Float16)W1[idx];
    }
    // ---- pair-index table: tab_s[p] = i | j<<8 (slots >= NP stay 0) ----
    for (int p = t; p < NTILE * 16; p += BLOCK) {
        unsigned short v = 0;
        if (p < NP) {
            int rem = p, i = 0;
            while (rem >= NF - 1 - i) { rem -= NF - 1 - i; ++i; }
            v = (unsigned short)(i | ((i + 1 + rem) << 8));
        }
        tab_s[p] = v;
    }

    const int r = blockIdx.x * RPB + lr;     // this wave's batch row
    const bool active = (r < B);

    _Float16 (* __restrict__ emb)[ESTRIDE] = emb_all[lr];
    float lin = 0.f;

    __syncthreads();          // w1t_s/tab_s/emb_all visible

    if (active) {
        // ---- linear part: computed by the h==0 wave of each row ----
        if (h == 0) {
            if (lane < NF) {
                lin = ltab[sparse[r * NF + lane]];
            } else if (lane >= 32 && lane < 32 + NDENSE) {
                int k = lane - 32;
                lin = dense[r * NDENSE + k] * wdense[k];
            }
            #pragma unroll
            for (int off = 32; off >= 1; off >>= 1) lin += __shfl_xor(lin, off, 64);
            lin += bias[0];
        }

        // b1/w2 for af = nt*16 + qd*4 + rr  (C-row mapping)
        float4 b1v4[4], w2v4[4];
        #pragma unroll
        for (int nt = 0; nt < 4; ++nt) {
            b1v4[nt] = *(const float4*)(b1 + nt * 16 + qd * 4);
            w2v4[nt] = *(const float4*)(w2 + nt * 16 + qd * 4);
        }

        // ---- W1^T A-operand fragments from LDS:
        //      bfr[nt][kh] = w1t[af = nt*16+ln][k = kh*32 + qd*8 + j] ----
        half8 bfr[4][2];
        #pragma unroll
        for (int nt = 0; nt < 4; ++nt)
            #pragma unroll
            for (int kh = 0; kh < 2; ++kh)
                bfr[nt][kh] = *(const half8*)(&w1t_s[nt * 16 + ln][kh * 32 + qd * 8]);

        // ---- fused main loop over this wave's 11 m-tiles (tbase = h*11).
        //      Lane state: m, l, acc0/acc1 (f16, dims qd*8..+7 / 32+qd*8..+7).
        //      Depth-1 pipeline: prefetch next tile's tab+emb fragments. ----
        const int tbase = h * NHT;
        float m = -INFINITY, l = 0.f;
        half8 acc0 = bcast8(0.f), acc1 = bcast8(0.f);

        unsigned pp = tab_s[tbase * 16 + ln];
        int fi = pp & 0xff, fj = pp >> 8;
        half8 ei0 = *(const half8*)(&emb[fi][qd * 8]);
        half8 ei1 = *(const half8*)(&emb[fi][32 + qd * 8]);
        half8 ej0 = *(const half8*)(&emb[fj][qd * 8]);
        half8 ej1 = *(const half8*)(&emb[fj][32 + qd * 8]);

        for (int k = 0; k < NHT; ++k) {
            half8 x0 = ei0 * ej0;                    // pair product, in registers
            half8 x1 = ei1 * ej1;

            if (k + 1 < NHT) {                       // issue next tile's loads now
                unsigned np = tab_s[(tbase + k + 1) * 16 + ln];
                int nfi = np & 0xff, nfj = np >> 8;
                ei0 = *(const half8*)(&emb[nfi][qd * 8]);
                ei1 = *(const half8*)(&emb[nfi][32 + qd * 8]);
                ej0 = *(const half8*)(&emb[nfj][qd * 8]);
                ej1 = *(const half8*)(&emb[nfj][32 + qd * 8]);
            }

            // logits: D[m=af][n=pair=ln]; C rows = qd*4+reg = af within nt*16.
            // Per-nt partials + 2-level tree (short dep chain).
            float lgp[4];
            #pragma unroll
            for (int nt = 0; nt < 4; ++nt) {
                f32x4 acc = { b1v4[nt].x, b1v4[nt].y, b1v4[nt].z, b1v4[nt].w };
                acc = __builtin_amdgcn_mfma_f32_16x16x32_f16(bfr[nt][0], x0, acc, 0, 0, 0);
                acc = __builtin_amdgcn_mfma_f32_16x16x32_f16(bfr[nt][1], x1, acc, 0, 0, 0);
                float u = fmaf(fmaxf(acc[1], 0.f), w2v4[nt].y, fmaxf(acc[0], 0.f) * w2v4[nt].x);
                float v = fmaf(fmaxf(acc[3], 0.f), w2v4[nt].w, fmaxf(acc[2], 0.f) * w2v4[nt].z);
                lgp[nt] = u + v;
            }
            float lg = (lgp[0] + lgp[1]) + (lgp[2] + lgp[3]);
            // sum over the 4 qd groups -> full 64-af logit, replicated across qd
            lg += __shfl_xor(lg, 16, 64);
            lg += __shfl_xor(lg, 32, 64);

            const int p0 = (tbase + k) * 16 + ln;
            if (p0 >= NP) lg = -INFINITY;            // pad pairs contribute 0

            // online-softmax update (per-lane running state)
            float mn    = fmaxf(m, lg);
            float alpha = __expf(m - mn);            // m=-inf first iter -> 0
            float e     = __expf(lg - mn);           // lg=-inf pad -> 0
            l = l * alpha + e;
            m = mn;
            half8 a8 = bcast8(alpha);
            half8 e8 = bcast8(e);
            acc0 = acc0 * a8 + x0 * e8;              // v_pk_fma_f16
            acc1 = acc1 * a8 + x1 * e8;
        }

        // ---- in-wave merge: ln bits cover this wave's 176 pair slots ----
        float mg = m;
        #pragma unroll
        for (int off = 1; off <= 8; off <<= 1) mg = fmaxf(mg, __shfl_xor(mg, off, 64));
        const float fac = __expf(m - mg);            // per-lane rescale to wave max
        float lsum = l * fac;
        #pragma unroll
        for (int off = 1; off <= 8; off <<= 1) lsum += __shfl_xor(lsum, off, 64);
        // mg/lsum now uniform across the wave (all qd groups see same pairs)

        // proj-dot in-lane (dims qd*8..+7 and 32+qd*8..+7), scaled by fac
        float4 pa4 = *(const float4*)(proj + qd * 8);
        float4 pb4 = *(const float4*)(proj + qd * 8 + 4);
        float4 pc4 = *(const float4*)(proj + 32 + qd * 8);
        float4 pd4 = *(const float4*)(proj + 32 + qd * 8 + 4);
        float rr = (float)acc0[0] * pa4.x + (float)acc0[1] * pa4.y
                 + (float)acc0[2] * pa4.z + (float)acc0[3] * pa4.w
                 + (float)acc0[4] * pb4.x + (float)acc0[5] * pb4.y
                 + (float)acc0[6] * pb4.z + (float)acc0[7] * pb4.w
                 + (float)acc1[0] * pc4.x + (float)acc1[1] * pc4.y
                 + (float)acc1[2] * pc4.z + (float)acc1[3] * pc4.w
                 + (float)acc1[4] * pd4.x + (float)acc1[5] * pd4.y
                 + (float)acc1[6] * pd4.z + (float)acc1[7] * pd4.w;
        rr *= fac;
        // sum over ln (pairs) and qd (dim chunks): all 6 lane bits
        #pragma unroll
        for (int off = 1; off <= 32; off <<= 1) rr += __shfl_xor(rr, off, 64);

        if (lane == 0) {
            red_s[wave][0] = mg;
            red_s[wave][1] = lsum;
            red_s[wave][2] = rr;
        }
    }

    __syncthreads();          // partner wave's (m,l,rr) visible

    // ---- flash 2-partition combine: h==0 wave of each row writes out ----
    if (active && h == 0 && lane == 0) {
        float m0 = red_s[wave][0],     l0 = red_s[wave][1],     r0 = red_s[wave][2];
        float m1 = red_s[wave + 1][0], l1 = red_s[wave + 1][1], r1 = red_s[wave + 1][2];
        float mg = fmaxf(m0, m1);
        float f0 = __expf(m0 - mg), f1 = __expf(m1 - mg);
        out[r] = lin + (r0 * f0 + r1 * f1) / (l0 * f0 + l1 * f1);
    }
}

extern "C" void kernel_launch(void* const* d_in, const int* in_sizes, int n_in,
                              void* d_out, int out_size, void* d_ws, size_t ws_size,
                              hipStream_t stream) {
    const int*   sparse = (const int*)  d_in[0];
    const float* dense  = (const float*)d_in[1];
    const float* etab   = (const float*)d_in[2];
    const float* ltab   = (const float*)d_in[3];
    const float* wdense = (const float*)d_in[4];
    const float* bias   = (const float*)d_in[5];
    const float* W1     = (const float*)d_in[6];
    const float* b1     = (const float*)d_in[7];
    const float* w2     = (const float*)d_in[8];
    const float* proj   = (const float*)d_in[9];
    float* outp = (float*)d_out;

    const int B = in_sizes[0] / NF;

    afm_kernel<<<dim3((B + RPB - 1) / RPB), dim3(BLOCK), 0, stream>>>(
        sparse, dense, etab, ltab, wdense, bias, W1, b1, w2, proj, outp, B);
    (void)n_in; (void)out_size; (void)d_ws; (void)ws_size;
}

// Round 4
// 110.436 us; speedup vs baseline: 3.2581x; 3.2581x over previous
//
#include <hip/hip_runtime.h>
#include <math.h>

// AFM forward: out[b] = linear(b) + softmax-weighted pair-interaction projection.
// B=4096, F=26, d=64, P=325 pairs, af=64.
//
// R11: back to the proven R8 skeleton (1 row/wave, 4 waves/block, 21 m-tiles,
// depth-1 fragment prefetch), plus three stall fixes. R10 post-mortem: 585 MB
// scratch writes / 385 MB refetch per dispatch = register-spill catastrophe at
// the 128-VGPR cap forced by __launch_bounds__(256,4); R9 already spilled
// mildly (17 MB). Fixes:
//  (a) __launch_bounds__(256,2): VGPR cap 256 -> spills structurally gone.
//      (Measured avg residency was 8.8 waves/CU, so the nominal cap is free.)
//  (b) cross-qd logit sums via v_permlane16/32_swap (VALU pipe) instead of
//      __shfl_xor (ds_bpermute: its lgkmcnt wait also drained the prefetched
//      emb loads each tile, lock-stepping the loop). r=swap(x,x): r0+r1 is
//      the xor-sum, branch-free, 2 VALU ops. __has_builtin-guarded.
//  (c) softmax update pipelined one tile behind the logit chain: the only
//      true recurrence is the ~50cyc (m,l,acc) update; the ~200cyc MFMA->
//      logit chain of tile k overlaps S(k-1).
// lin moved to the epilogue (shorter live ranges through the loop).

#define NF 26
#define NP 325
#define NMT 21           // 21 m-tiles of 16 pairs (336, pads -> -inf)
#define ED 64
#define AF 64
#define NDENSE 13
#define WPB 4            // waves (rows) per block
#define BLOCK (WPB * 64)
#define ESTRIDE 72       // f16 elems per emb row: 144 B (16B-aligned rows)
#define WSTRIDE 72       // f16 elems per w1t row: 144 B (16B-aligned rows)

typedef __attribute__((ext_vector_type(8))) _Float16 half8;
typedef __attribute__((ext_vector_type(4))) float f32x4;

__device__ __forceinline__ half8 bcast8(float v) {
    _Float16 hh = (_Float16)v;
    half8 r = { hh, hh, hh, hh, hh, hh, hh, hh };
    return r;
}

// Sum across the qd lane-groups (lane bits 4,5). permlane*_swap runs on the
// VALU pipe (no lgkmcnt interaction); swap(x,x) returns (even-group bcast,
// odd-group bcast), so r0+r1 = xor-sum, uniform across lanes.
__device__ __forceinline__ float qd_sum(float x) {
#if __has_builtin(__builtin_amdgcn_permlane16_swap) && __has_builtin(__builtin_amdgcn_permlane32_swap)
    {
        auto a = __builtin_amdgcn_permlane16_swap(__builtin_bit_cast(unsigned, x),
                                                  __builtin_bit_cast(unsigned, x),
                                                  false, false);
        x = __builtin_bit_cast(float, a[0]) + __builtin_bit_cast(float, a[1]);
        auto b = __builtin_amdgcn_permlane32_swap(__builtin_bit_cast(unsigned, x),
                                                  __builtin_bit_cast(unsigned, x),
                                                  false, false);
        x = __builtin_bit_cast(float, b[0]) + __builtin_bit_cast(float, b[1]);
    }
#else
    x += __shfl_xor(x, 16, 64);
    x += __shfl_xor(x, 32, 64);
#endif
    return x;
}

__global__ __launch_bounds__(BLOCK, 2)   // cap 256 VGPR: spills are the enemy (R10)
void afm_kernel(const int*   __restrict__ sparse,   // [B,26]
                const float* __restrict__ dense,    // [B,13]
                const float* __restrict__ etab,     // [V,64]
                const float* __restrict__ ltab,     // [V]
                const float* __restrict__ wdense,   // [13]
                const float* __restrict__ bias,     // [1]
                const float* __restrict__ W1,       // [64][64] f32, d-major
                const float* __restrict__ b1,       // [64]
                const float* __restrict__ w2,       // [64]
                const float* __restrict__ proj,     // [64]
                float*       __restrict__ out,      // [B]
                int B)
{
    const int t    = threadIdx.x;
    const int wave = t >> 6;
    const int lane = t & 63;
    const int qd   = lane >> 4;     // quad 0..3
    const int ln   = lane & 15;

    __shared__ alignas(16) _Float16       w1t_s[AF][WSTRIDE];        // 9216 B
    __shared__              unsigned short tab_s[NMT * 16];          //  672 B
    __shared__ alignas(16) _Float16       emb_all[WPB][NF][ESTRIDE]; // 14976 B

    // ---- block-cooperative embedding staging: WPB rows spread evenly over
    //      256 threads (832 tasks), f32 gather -> f16 b128 LDS writes ----
    for (int task = t; task < WPB * NF * 8; task += BLOCK) {
        int w   = task / (NF * 8);
        int rem = task - w * (NF * 8);
        int f = rem >> 3, c = rem & 7;                   // 8-half chunk
        int rw = blockIdx.x * WPB + w;
        if (rw < B) {
            const float* src = etab + (size_t)sparse[rw * NF + f] * ED + c * 8;
            float4 v0 = *(const float4*)(src);
            float4 v1 = *(const float4*)(src + 4);
            half8 hv = { (_Float16)v0.x, (_Float16)v0.y, (_Float16)v0.z, (_Float16)v0.w,
                         (_Float16)v1.x, (_Float16)v1.y, (_Float16)v1.z, (_Float16)v1.w };
            *(half8*)(&emb_all[w][f][c * 8]) = hv;
        }
    }
    // ---- block-cooperative W1 -> W1^T staging (L2-hot 16 KB) ----
    for (int idx = t; idx < ED * AF; idx += BLOCK) {
        int d = idx >> 6, a = idx & 63;       // W1 is [d][a]
        w1t_s[a][d] = (_Float16)W1[idx];
    }
    // ---- pair-index table: tab_s[p] = i | j<<8 (slots >= NP stay 0) ----
    for (int p = t; p < NMT * 16; p += BLOCK) {
        unsigned short v = 0;
        if (p < NP) {
            int rem = p, i = 0;
            while (rem >= NF - 1 - i) { rem -= NF - 1 - i; ++i; }
            v = (unsigned short)(i | ((i + 1 + rem) << 8));
        }
        tab_s[p] = v;
    }

    const int r = blockIdx.x * WPB + wave;   // this wave's batch row
    const bool active = (r < B);

    _Float16 (* __restrict__ emb)[ESTRIDE] = emb_all[wave];

    __syncthreads();          // w1t_s/tab_s/emb_all visible
    if (!active) return;      // safe: no barriers after this point

    // b1/w2 for af = nt*16 + qd*4 + rr  (C-row mapping)
    float4 b1v4[4], w2v4[4];
    #pragma unroll
    for (int nt = 0; nt < 4; ++nt) {
        b1v4[nt] = *(const float4*)(b1 + nt * 16 + qd * 4);
        w2v4[nt] = *(const float4*)(w2 + nt * 16 + qd * 4);
    }

    // ---- W1^T A-operand fragments from LDS:
    //      bfr[nt][kh] = w1t[af = nt*16+ln][k = kh*32 + qd*8 + j] ----
    half8 bfr[4][2];
    #pragma unroll
    for (int nt = 0; nt < 4; ++nt)
        #pragma unroll
        for (int kh = 0; kh < 2; ++kh)
            bfr[nt][kh] = *(const half8*)(&w1t_s[nt * 16 + ln][kh * 32 + qd * 8]);

    // ---- fused main loop, software-pipelined: G(k) computes tile-k logit
    //      while S(k-1) performs the serial softmax/accumulator update. ----
    float m = -INFINITY, l = 0.f;
    half8 acc0 = bcast8(0.f), acc1 = bcast8(0.f);

    // tile-0 fragment loads
    {
        unsigned pp = tab_s[ln];
        int fi = pp & 0xff, fj = pp >> 8;
        (void)fi; (void)fj;
    }
    unsigned pp0 = tab_s[ln];
    int fi0 = pp0 & 0xff, fj0 = pp0 >> 8;
    half8 eiR0 = *(const half8*)(&emb[fi0][qd * 8]);
    half8 eiR1 = *(const half8*)(&emb[fi0][32 + qd * 8]);
    half8 ejR0 = *(const half8*)(&emb[fj0][qd * 8]);
    half8 ejR1 = *(const half8*)(&emb[fj0][32 + qd * 8]);

    float lgP = 0.f;
    half8 xP0 = bcast8(0.f), xP1 = bcast8(0.f);

    for (int k = 0; k < NMT; ++k) {
        // finish L(k): build current pair products (waits on frag loads)
        half8 xC0 = eiR0 * ejR0;
        half8 xC1 = eiR1 * ejR1;

        // issue L(k+1): next tile's fragment loads (eiR/ejR dead after x build)
        if (k + 1 < NMT) {
            unsigned np = tab_s[(k + 1) * 16 + ln];
            int nfi = np & 0xff, nfj = np >> 8;
            eiR0 = *(const half8*)(&emb[nfi][qd * 8]);
            eiR1 = *(const half8*)(&emb[nfi][32 + qd * 8]);
            ejR0 = *(const half8*)(&emb[nfj][qd * 8]);
            ejR1 = *(const half8*)(&emb[nfj][32 + qd * 8]);
        }

        // G(k): logits. D[m=af][n=pair=ln]; C rows = qd*4+reg = af in nt*16.
        float lgp[4];
        #pragma unroll
        for (int nt = 0; nt < 4; ++nt) {
            f32x4 acc = { b1v4[nt].x, b1v4[nt].y, b1v4[nt].z, b1v4[nt].w };
            acc = __builtin_amdgcn_mfma_f32_16x16x32_f16(bfr[nt][0], xC0, acc, 0, 0, 0);
            acc = __builtin_amdgcn_mfma_f32_16x16x32_f16(bfr[nt][1], xC1, acc, 0, 0, 0);
            float u = fmaf(fmaxf(acc[1], 0.f), w2v4[nt].y, fmaxf(acc[0], 0.f) * w2v4[nt].x);
            float v = fmaf(fmaxf(acc[3], 0.f), w2v4[nt].w, fmaxf(acc[2], 0.f) * w2v4[nt].z);
            lgp[nt] = u + v;
        }
        float lg = (lgp[0] + lgp[1]) + (lgp[2] + lgp[3]);
        lg = qd_sum(lg);                         // full 64-af logit, all lanes
        if (k * 16 + ln >= NP) lg = -INFINITY;   // pad pairs contribute 0

        // S(k-1): serial online-softmax update (the only loop recurrence)
        if (k > 0) {
            float mn    = fmaxf(m, lgP);
            float alpha = __expf(m - mn);        // m=-inf first time -> 0
            float e     = __expf(lgP - mn);      // lgP=-inf pad -> 0
            l = l * alpha + e;
            m = mn;
            half8 a8 = bcast8(alpha), e8 = bcast8(e);
            acc0 = acc0 * a8 + xP0 * e8;         // v_pk_fma_f16
            acc1 = acc1 * a8 + xP1 * e8;
        }
        // rotate pipeline state
        xP0 = xC0; xP1 = xC1; lgP = lg;
    }
    // S(NMT-1): drain the pipeline
    {
        float mn    = fmaxf(m, lgP);
        float alpha = __expf(m - mn);
        float e     = __expf(lgP - mn);
        l = l * alpha + e;
        m = mn;
        half8 a8 = bcast8(alpha), e8 = bcast8(e);
        acc0 = acc0 * a8 + xP0 * e8;
        acc1 = acc1 * a8 + xP1 * e8;
    }

    // ---- linear part (epilogue; overlaps the merge below) ----
    float lin = 0.f;
    if (lane < NF) {
        lin = ltab[sparse[r * NF + lane]];
    } else if (lane >= 32 && lane < 32 + NDENSE) {
        int k = lane - 32;
        lin = dense[r * NDENSE + k] * wdense[k];
    }
    #pragma unroll
    for (int off = 32; off >= 1; off >>= 1) lin += __shfl_xor(lin, off, 64);
    lin += bias[0];

    // ---- merge: lanes sharing qd (ln = bits 0..3) cover all 336 slots ----
    float mg = m;
    #pragma unroll
    for (int off = 1; off <= 8; off <<= 1) mg = fmaxf(mg, __shfl_xor(mg, off, 64));
    const float fac = __expf(m - mg);            // per-lane rescale to global max
    float lsum = l * fac;
    #pragma unroll
    for (int off = 1; off <= 8; off <<= 1) lsum += __shfl_xor(lsum, off, 64);
    // lsum now = global softmax denominator, identical across qd groups

    // proj-dot in-lane (dims qd*8..+7 and 32+qd*8..+7), scaled by fac
    float4 pa4 = *(const float4*)(proj + qd * 8);
    float4 pb4 = *(const float4*)(proj + qd * 8 + 4);
    float4 pc4 = *(const float4*)(proj + 32 + qd * 8);
    float4 pd4 = *(const float4*)(proj + 32 + qd * 8 + 4);
    float rr = (float)acc0[0] * pa4.x + (float)acc0[1] * pa4.y
             + (float)acc0[2] * pa4.z + (float)acc0[3] * pa4.w
             + (float)acc0[4] * pb4.x + (float)acc0[5] * pb4.y
             + (float)acc0[6] * pb4.z + (float)acc0[7] * pb4.w
             + (float)acc1[0] * pc4.x + (float)acc1[1] * pc4.y
             + (float)acc1[2] * pc4.z + (float)acc1[3] * pc4.w
             + (float)acc1[4] * pd4.x + (float)acc1[5] * pd4.y
             + (float)acc1[6] * pd4.z + (float)acc1[7] * pd4.w;
    rr *= fac;
    // sum over ln (pairs) and qd (dim chunks): all 6 lane bits
    #pragma unroll
    for (int off = 1; off <= 32; off <<= 1) rr += __shfl_xor(rr, off, 64);

    if (lane == 0) out[r] = lin + rr / lsum;
}

extern "C" void kernel_launch(void* const* d_in, const int* in_sizes, int n_in,
                              void* d_out, int out_size, void* d_ws, size_t ws_size,
                              hipStream_t stream) {
    const int*   sparse = (const int*)  d_in[0];
    const float* dense  = (const float*)d_in[1];
    const float* etab   = (const float*)d_in[2];
    const float* ltab   = (const float*)d_in[3];
    const float* wdense = (const float*)d_in[4];
    const float* bias   = (const float*)d_in[5];
    const float* W1     = (const float*)d_in[6];
    const float* b1     = (const float*)d_in[7];
    const float* w2     = (const float*)d_in[8];
    const float* proj   = (const float*)d_in[9];
    float* outp = (float*)d_out;

    const int B = in_sizes[0] / NF;

    afm_kernel<<<dim3((B + WPB - 1) / WPB), dim3(BLOCK), 0, stream>>>(
        sparse, dense, etab, ltab, wdense, bias, W1, b1, w2, proj, outp, B);
    (void)n_in; (void)out_size; (void)d_ws; (void)ws_size;
}